// Round 13
// baseline (8125.309 us; speedup 1.0000x reference)
//
#include <hip/hip_runtime.h>

#define NB 256
#define NT 256
#define AGT __HIP_MEMORY_SCOPE_AGENT
typedef unsigned long long ull;
typedef _Float16 f16;
typedef __attribute__((ext_vector_type(8))) _Float16 f16x8;
typedef __attribute__((ext_vector_type(4))) float f32x4;
typedef __attribute__((ext_vector_type(4))) unsigned u32x4;

// B=32, S=24, T=48, hidden 512, gate dim 2048.
// 8 teams x 4 batches (team=w>>5, slot=w&31). Slot owns units 16s..16s+15.
// GATE-MAJOR row map grow(r)=(r&3)*512+slot*16+(r>>2). Wave wq owns units
// 4wq..4wq+3 COMPLETELY (MFMA rows, cell state, stores are wave-local).
// R13: WAVE-DECOUPLED fused loop - each wave stages the full exchange tile
// into its OWN private LDS tile (4x redundant reads; R9=R12 proved load
// mechanics aren't the limiter) -> ZERO __syncthreads in the 49-iter loop.
// Sketch X pre-staged per stroke in the (sync'd) t0 phase; lens hoisted.
// Parity WAR safety holds at wave granularity (skew <= 1 phase).
// Exchange: seq-embedded 8B chunks (4B fp16x2 + 4B seq); 16B asm loads for
// wave staging, compiler agent atomics for stores & shared staging.

#define BSTR 1056   // B-tile row stride in bytes (528 shorts)

struct __align__(16) SMem {
  unsigned short Wv[4][2][4 * 528]; // per-wave [B0,B1] tiles (33.8KB)
  unsigned short Bs[2][4 * 528];    // shared staging (scene/t0/init)
  float Xs[48][4][8];               // stroke's sketch tokens (staged at t0)
  float X0[4][8];                   // t0 token
  int sLens[2][4];
  int sLmax[2];
};

__device__ __forceinline__ float sigm(float x) { return 1.0f / (1.0f + expf(-x)); }
__device__ __forceinline__ unsigned short f16b(float x) {
  union { _Float16 h; unsigned short u; } q; q.h = (_Float16)x; return q.u;
}
__device__ __forceinline__ ull pk4(float a, float b, float c, float d) {
  union { _Float16 h; unsigned short u; } q;
  ull r; q.h = (_Float16)a; r = q.u; q.h = (_Float16)b; r |= (ull)q.u << 16;
  q.h = (_Float16)c; r |= (ull)q.u << 32; q.h = (_Float16)d; r |= (ull)q.u << 48;
  return r;
}
__device__ __forceinline__ ull lda8(const ull* p) {
  return __hip_atomic_load(p, __ATOMIC_RELAXED, AGT);
}
__device__ __forceinline__ u32x4 ld1x16(const void* p) {
  u32x4 r;
  asm volatile("global_load_dwordx4 %0, %1, off sc0 sc1\ns_waitcnt vmcnt(0)"
               : "=&v"(r) : "v"(p) : "memory");
  return r;
}
__device__ __forceinline__ void issue4(const void* p0, const void* p1,
                                       const void* p2, const void* p3,
                                       u32x4& a, u32x4& b, u32x4& c, u32x4& d) {
  asm volatile("global_load_dwordx4 %0, %4, off sc0 sc1\n"
               "global_load_dwordx4 %1, %5, off sc0 sc1\n"
               "global_load_dwordx4 %2, %6, off sc0 sc1\n"
               "global_load_dwordx4 %3, %7, off sc0 sc1"
               : "=&v"(a), "=&v"(b), "=&v"(c), "=&v"(d)
               : "v"(p0), "v"(p1), "v"(p2), "v"(p3) : "memory");
}

extern "C" __global__ void __launch_bounds__(NT, 1)
rnn_decoder_kernel(const float* __restrict__ enc, const float* __restrict__ sketch,
                   const int* __restrict__ slen,
                   const float* __restrict__ Wsc_ih, const float* __restrict__ Wsc_hh,
                   const float* __restrict__ bsc,
                   const float* __restrict__ W0ih, const float* __restrict__ W0hh,
                   const float* __restrict__ b0,
                   const float* __restrict__ W1ih, const float* __restrict__ W1hh,
                   const float* __restrict__ b1,
                   const float* __restrict__ Wout, const float* __restrict__ bout,
                   float* __restrict__ out, float* __restrict__ ws)
{
  extern __shared__ char smraw[];
  SMem* sm = (SMem*)smraw;
  const int tid = threadIdx.x;
  const int w = blockIdx.x;
  const int team = w >> 5, slot = w & 31;
  const int lane = tid & 63;
  const int wq = tid >> 6;
  const int l15 = lane & 15;
  const int kq = lane >> 4;
  const int my_b = l15 & 3;
  const int my_u = wq * 4 + kq;

  ull* tb = (ull*)ws + (size_t)team * 6144;
  ull* h0T = tb;
  ull* h1T = tb + 2048;
  ull* sHg = tb + 4096;

  auto grow = [&](int r) { return ((r & 3) << 9) + slot * 16 + (r >> 2); };

  auto ldsB = [&](const unsigned short* Bp, int st) -> f16x8 {
    return *(const f16x8*)((const char*)Bp + my_b * BSTR + st * 64 + kq * 16);
  };
  auto mfma_gv = [&](const float* W, int stride, int coloff, const unsigned short* Bp, f32x4& acc) {
    const float* rp = W + (size_t)grow(wq * 16 + l15) * stride + coloff;
#pragma unroll
    for (int st = 0; st < 16; ++st) {
      const float* q = rp + st * 32 + kq * 8;
      float4 u0 = *(const float4*)q, u1 = *(const float4*)(q + 4);
      f16x8 a;
      a[0] = (f16)u0.x; a[1] = (f16)u0.y; a[2] = (f16)u0.z; a[3] = (f16)u0.w;
      a[4] = (f16)u1.x; a[5] = (f16)u1.y; a[6] = (f16)u1.z; a[7] = (f16)u1.w;
      acc = __builtin_amdgcn_mfma_f32_16x16x32_f16(a, ldsB(Bp, st), acc, 0, 0, 0);
    }
  };
  auto mfma_gs = [&](const float* W, const unsigned short* Bp, f32x4& acc) {
    const float* rp = W + (size_t)grow(wq * 16 + l15) * 517;
#pragma unroll
    for (int st = 0; st < 16; ++st) {
      const float* q = rp + st * 32 + kq * 8;
      f16x8 a;
#pragma unroll
      for (int j = 0; j < 8; ++j) a[j] = (f16)q[j];
      acc = __builtin_amdgcn_mfma_f32_16x16x32_f16(a, ldsB(Bp, st), acc, 0, 0, 0);
    }
  };

  // ---------- shared staging (scene/t0/init; block-wide, sync'd outside) ----------
  auto stage4 = [&](const ull* s0, unsigned e0, unsigned short* Bp) {
    const ull* pA = s0 + 2 * tid;
    const ull* pB = pA + 1;
    const ull* pC = s0 + 512 + 2 * tid;
    const ull* pD = pC + 1;
    ull a = lda8(pA), b = lda8(pB), c = lda8(pC), d = lda8(pD);
    int spins = 0;
    while ((((unsigned)(a >> 32) ^ e0) | ((unsigned)(b >> 32) ^ e0) |
            ((unsigned)(c >> 32) ^ e0) | ((unsigned)(d >> 32) ^ e0)) != 0) {
      if (++spins > 40000) break;          // bailout: garbage > hang
      if (spins > 16) __builtin_amdgcn_s_sleep(1);
      if ((unsigned)(a >> 32) != e0) a = lda8(pA);
      if ((unsigned)(b >> 32) != e0) b = lda8(pB);
      if ((unsigned)(c >> 32) != e0) c = lda8(pC);
      if ((unsigned)(d >> 32) != e0) d = lda8(pD);
    }
    {
      int bb2 = tid >> 7, up = (2 * tid) & 255;
      *(ull*)((char*)Bp + bb2 * BSTR + up * 4) =
          (ull)(unsigned)a | ((ull)(unsigned)b << 32);
      int t2 = tid + 256;
      int bb3 = t2 >> 7, up2 = (2 * t2) & 255;
      *(ull*)((char*)Bp + bb3 * BSTR + up2 * 4) =
          (ull)(unsigned)c | ((ull)(unsigned)d << 32);
    }
  };

  // ---------- per-wave staging: lane covers chunks 16*lane..16*lane+15 ----------
  auto stageW = [&](const ull* s0, unsigned e0, unsigned short* Wt) {
    const char* p = (const char*)(s0 + 16 * lane);
    u32x4 v0, v1, v2, v3, v4, v5, v6, v7;
    issue4(p, p + 16, p + 32, p + 48, v0, v1, v2, v3);
    issue4(p + 64, p + 80, p + 96, p + 112, v4, v5, v6, v7);
    asm volatile("s_waitcnt vmcnt(0)"
                 : "+v"(v0), "+v"(v1), "+v"(v2), "+v"(v3),
                   "+v"(v4), "+v"(v5), "+v"(v6), "+v"(v7) :: "memory");
    int spins = 0;
    for (;;) {
      unsigned bad = (v0.y ^ e0) | (v0.w ^ e0) | (v1.y ^ e0) | (v1.w ^ e0) |
                     (v2.y ^ e0) | (v2.w ^ e0) | (v3.y ^ e0) | (v3.w ^ e0) |
                     (v4.y ^ e0) | (v4.w ^ e0) | (v5.y ^ e0) | (v5.w ^ e0) |
                     (v6.y ^ e0) | (v6.w ^ e0) | (v7.y ^ e0) | (v7.w ^ e0);
      if (!bad) break;
      if (++spins > 40000) break;          // bailout: garbage > hang
      if (spins > 16) __builtin_amdgcn_s_sleep(1);
      if ((v0.y ^ e0) | (v0.w ^ e0)) v0 = ld1x16(p);
      if ((v1.y ^ e0) | (v1.w ^ e0)) v1 = ld1x16(p + 16);
      if ((v2.y ^ e0) | (v2.w ^ e0)) v2 = ld1x16(p + 32);
      if ((v3.y ^ e0) | (v3.w ^ e0)) v3 = ld1x16(p + 48);
      if ((v4.y ^ e0) | (v4.w ^ e0)) v4 = ld1x16(p + 64);
      if ((v5.y ^ e0) | (v5.w ^ e0)) v5 = ld1x16(p + 80);
      if ((v6.y ^ e0) | (v6.w ^ e0)) v6 = ld1x16(p + 96);
      if ((v7.y ^ e0) | (v7.w ^ e0)) v7 = ld1x16(p + 112);
    }
    char* d = (char*)Wt + (lane >> 4) * BSTR + 64 * l15;
    *(ull*)(d)      = (ull)v0.x | ((ull)v0.z << 32);
    *(ull*)(d + 8)  = (ull)v1.x | ((ull)v1.z << 32);
    *(ull*)(d + 16) = (ull)v2.x | ((ull)v2.z << 32);
    *(ull*)(d + 24) = (ull)v3.x | ((ull)v3.z << 32);
    *(ull*)(d + 32) = (ull)v4.x | ((ull)v4.z << 32);
    *(ull*)(d + 40) = (ull)v5.x | ((ull)v5.z << 32);
    *(ull*)(d + 48) = (ull)v6.x | ((ull)v6.z << 32);
    *(ull*)(d + 56) = (ull)v7.x | ((ull)v7.z << 32);
  };

  // ---------- init: ALL recurrent weights into registers ----------
  f16x8 w0hh[16], w1ih[16], whh[16];
  {
    const float* r0 = W0hh + (size_t)grow(wq * 16 + l15) * 512;
    const float* r1 = W1ih + (size_t)grow(wq * 16 + l15) * 512;
    const float* r2 = W1hh + (size_t)grow(wq * 16 + l15) * 512;
#pragma unroll
    for (int st = 0; st < 16; ++st) {
      const int o = st * 32 + kq * 8;
      float4 u0, u1;
      f16x8 a;
      u0 = *(const float4*)(r0 + o); u1 = *(const float4*)(r0 + o + 4);
      a[0] = (f16)u0.x; a[1] = (f16)u0.y; a[2] = (f16)u0.z; a[3] = (f16)u0.w;
      a[4] = (f16)u1.x; a[5] = (f16)u1.y; a[6] = (f16)u1.z; a[7] = (f16)u1.w;
      w0hh[st] = a;
      u0 = *(const float4*)(r1 + o); u1 = *(const float4*)(r1 + o + 4);
      a[0] = (f16)u0.x; a[1] = (f16)u0.y; a[2] = (f16)u0.z; a[3] = (f16)u0.w;
      a[4] = (f16)u1.x; a[5] = (f16)u1.y; a[6] = (f16)u1.z; a[7] = (f16)u1.w;
      w1ih[st] = a;
      u0 = *(const float4*)(r2 + o); u1 = *(const float4*)(r2 + o + 4);
      a[0] = (f16)u0.x; a[1] = (f16)u0.y; a[2] = (f16)u0.z; a[3] = (f16)u0.w;
      a[4] = (f16)u1.x; a[5] = (f16)u1.y; a[6] = (f16)u1.z; a[7] = (f16)u1.w;
      whh[st] = a;
    }
  }
  float cb0[4], cb1[4], cbsc[4], cwx[4][5];
  {
    int gu = slot * 16 + my_u;
#pragma unroll
    for (int gi = 0; gi < 4; ++gi) {
      int gr = gi * 512 + gu;
      cb0[gi] = b0[gr]; cb1[gi] = b1[gr]; cbsc[gi] = bsc[gr];
#pragma unroll
      for (int j = 0; j < 5; ++j) cwx[gi][j] = W0ih[(size_t)gr * 517 + 512 + j];
    }
  }
  const int b_o = slot / 5, o_o = slot % 5;
  const bool oslot = (slot < 20);
  const int owave = slot & 3;               // which wave does the out-dot
  float wo[8]; float bo_r = 0.f;
  if (oslot) {
    bo_r = bout[o_o];
#pragma unroll
    for (int j = 0; j < 8; ++j) wo[j] = Wout[o_o * 512 + lane * 8 + j];
  }

  // e0reg = Wsc_ih[:, :512] @ enc  -> per-lane f32x4
  f32x4 e0reg = {0.f, 0.f, 0.f, 0.f};
  {
    int b2 = tid >> 6, c8 = tid & 63;
    const float* q = enc + (size_t)(4 * team + b2) * 512 + c8 * 8;
    float4 u0 = *(const float4*)q, u1 = *(const float4*)(q + 4);
    unsigned short* Bp = &sm->Bs[0][0];
    *(ull*)((char*)Bp + b2 * BSTR + c8 * 16) = pk4(u0.x, u0.y, u0.z, u0.w);
    *(ull*)((char*)Bp + b2 * BSTR + c8 * 16 + 8) = pk4(u1.x, u1.y, u1.z, u1.w);
    __syncthreads();
    mfma_gv(Wsc_ih, 1024, 0, Bp, e0reg);
  }

  float o_csc = 0.f, o_c0 = 0.f, o_h0 = 0.f, o_c1 = 0.f, o_h1 = 0.f;
  unsigned short* myB0 = &sm->Wv[wq][0][0];
  unsigned short* myB1 = &sm->Wv[wq][1][0];

  for (int s = 0; s < 24; ++s) {
    const unsigned base = 51u * (unsigned)s;

    // ================= scene phase (block-wide, sync'd) =================
    {
      int lv = (tid < 32) ? slen[tid * 24 + s] : 0;
      if (tid < 64) {
#pragma unroll
        for (int o2 = 1; o2 < 64; o2 <<= 1) lv = max(lv, __shfl_xor(lv, o2, 64));
        if (tid == 0) sm->sLmax[s & 1] = lv;
      }
      if (tid < 4) sm->sLens[s & 1][tid] = slen[(4 * team + tid) * 24 + s];
    }
    {
      unsigned short* Bp0 = &sm->Bs[0][0];
      unsigned short* Bp1 = &sm->Bs[1][0];
      if (s > 0) {
        stage4(h1T, base, Bp0);                              // final h1 (parity 0)
        stage4(sHg + ((s - 1) & 1) * 1024, base - 50u, Bp1); // scene_h(s-1)
      }
      __syncthreads();
      f32x4 asc = {0.f, 0.f, 0.f, 0.f};
      if (s > 0) {
        mfma_gv(Wsc_ih, 1024, 512, Bp0, asc);
        mfma_gv(Wsc_hh, 512, 0, Bp1, asc);
      }
      float g[4];
#pragma unroll
      for (int gi = 0; gi < 4; ++gi) g[gi] = e0reg[gi] + cbsc[gi] + asc[gi];
      float c = sigm(g[1]) * o_csc + sigm(g[0]) * tanhf(g[2]);
      float h = sigm(g[3]) * tanhf(c);
      o_csc = c;
      o_c0 = o_h0 = o_c1 = o_h1 = 0.f;
      float hhi = __shfl_down(h, 16, 64);
      if (((kq & 1) == 0) && (l15 < 4)) {
        int chunk = my_b * 256 + slot * 8 + wq * 2 + (kq >> 1);
        unsigned pay = (unsigned)f16b(h) | ((unsigned)f16b(hhi) << 16);
        __hip_atomic_store(&sHg[(s & 1) * 1024 + chunk],
                           (ull)pay | ((ull)(base + 1u) << 32), __ATOMIC_RELAXED, AGT);
      }
    }

    // ================= t0 pre-step (block-wide, sync'd) =================
    f32x4 s0reg = {0.f, 0.f, 0.f, 0.f};
    {
      __syncthreads();                      // Bs overwrite vs scene readers
      unsigned short* Bp0 = &sm->Bs[0][0];
      if (tid < 4) {
        float xv[5];
        if (s == 0) { xv[0] = 0.f; xv[1] = 0.f; xv[2] = 1.f; xv[3] = 0.f; xv[4] = 0.f; }
        else {
          int bgl = 4 * team + tid;
          int lp = slen[bgl * 24 + (s - 1)];
          int last = min(max(lp - 1, 0), 47);
          const float* q = sketch + ((bgl * 24 + (s - 1)) * 48 + last) * 5;
#pragma unroll
          for (int j = 0; j < 5; ++j) xv[j] = q[j];
        }
#pragma unroll
        for (int j = 0; j < 5; ++j) sm->X0[tid][j] = xv[j];
      }
      // stage the whole stroke's sketch tokens: Xs[k][b][j], k=0..47
      for (int e = tid; e < 960; e += NT) {
        int k2 = e / 20, r2 = e % 20, b2 = r2 / 5, j2 = r2 % 5;
        sm->Xs[k2][b2][j2] =
            sketch[(((4 * team + b2) * 24 + s) * 48 + k2) * 5 + j2];
      }
      stage4(sHg + (s & 1) * 1024, base + 1u, Bp0);
      __syncthreads();
      mfma_gs(W0ih, Bp0, s0reg);
      float g[4];
#pragma unroll
      for (int gi = 0; gi < 4; ++gi) {
        float xd = 0.f;
#pragma unroll
        for (int j = 0; j < 5; ++j) xd += cwx[gi][j] * sm->X0[my_b][j];
        g[gi] = s0reg[gi] + cb0[gi] + xd;
      }
      float c = sigm(g[1]) * o_c0 + sigm(g[0]) * tanhf(g[2]);
      o_c0 = c; o_h0 = sigm(g[3]) * tanhf(c);
      float hhi = __shfl_down(o_h0, 16, 64);
      if (((kq & 1) == 0) && (l15 < 4)) {
        int chunk = my_b * 256 + slot * 8 + wq * 2 + (kq >> 1);
        unsigned pay = (unsigned)f16b(o_h0) | ((unsigned)f16b(hhi) << 16);
        __hip_atomic_store(&h0T[chunk],
                           (ull)pay | ((ull)(base + 2u) << 32), __ATOMIC_RELAXED, AGT);
      }
    }

    // hoisted per-stroke constants (written before the last sync above)
    const int Lb = sm->sLens[s & 1][my_b];
    const int Lmax_s = sm->sLmax[s & 1];
    const int Lb_o = sm->sLens[s & 1][oslot ? b_o : 0];

    // ============ fused iterations: WAVE-DECOUPLED, no block syncs ============
    for (int k = 0; k <= 48; ++k) {
      const bool doL0 = (k < 48), doPrev = (k > 0);
      const unsigned eSeq = base + 2u + (unsigned)k, sSeq = eSeq + 1u;

      // ---- stage 1: own-wave staging of h0(k), W0hh MFMA, L0 cell, h0 store
      stageW(h0T + (k & 1) * 1024, eSeq, myB0);
      f32x4 a0 = {0.f, 0.f, 0.f, 0.f}, a1 = {0.f, 0.f, 0.f, 0.f};
      if (doL0) {
#pragma unroll
        for (int st = 0; st < 16; ++st)
          a0 = __builtin_amdgcn_mfma_f32_16x16x32_f16(w0hh[st], ldsB(myB0, st), a0, 0, 0, 0);
        if ((k + 1) <= Lb) {
          float g[4];
#pragma unroll
          for (int gi = 0; gi < 4; ++gi) {
            float xd = 0.f;
#pragma unroll
            for (int j = 0; j < 5; ++j) xd += cwx[gi][j] * sm->Xs[k][my_b][j];
            g[gi] = a0[gi] + s0reg[gi] + cb0[gi] + xd;
          }
          float c = sigm(g[1]) * o_c0 + sigm(g[0]) * tanhf(g[2]);
          o_c0 = c; o_h0 = sigm(g[3]) * tanhf(c);
        }
        float hhi0 = __shfl_down(o_h0, 16, 64);
        if (((kq & 1) == 0) && (l15 < 4)) {
          int chunk = my_b * 256 + slot * 8 + wq * 2 + (kq >> 1);
          unsigned p0 = (unsigned)f16b(o_h0) | ((unsigned)f16b(hhi0) << 16);
          __hip_atomic_store(&h0T[((k + 1) & 1) * 1024 + chunk],
                             (ull)p0 | ((ull)sSeq << 32), __ATOMIC_RELAXED, AGT);
        }
        asm volatile("" ::: "memory");
      }
#pragma unroll
      for (int st = 0; st < 16; ++st)
        a1 = __builtin_amdgcn_mfma_f32_16x16x32_f16(w1ih[st], ldsB(myB0, st), a1, 0, 0, 0);

      // ---- stage 2: own-wave staging of h1(k-1), W1hh MFMA, L1 cell, h1 store
      if (doPrev) {
        stageW(h1T + ((k - 1) & 1) * 1024, eSeq, myB1);
#pragma unroll
        for (int st = 0; st < 16; ++st)
          a1 = __builtin_amdgcn_mfma_f32_16x16x32_f16(whh[st], ldsB(myB1, st), a1, 0, 0, 0);
      }
      if (k <= Lb) {
        float g[4];
#pragma unroll
        for (int gi = 0; gi < 4; ++gi) g[gi] = a1[gi] + cb1[gi];
        float c = sigm(g[1]) * o_c1 + sigm(g[0]) * tanhf(g[2]);
        o_c1 = c; o_h1 = sigm(g[3]) * tanhf(c);
      }
      float hhi1 = __shfl_down(o_h1, 16, 64);
      if (((kq & 1) == 0) && (l15 < 4)) {
        int chunk = my_b * 256 + slot * 8 + wq * 2 + (kq >> 1);
        unsigned p1 = (unsigned)f16b(o_h1) | ((unsigned)f16b(hhi1) << 16);
        __hip_atomic_store(&h1T[(k & 1) * 1024 + chunk],
                           (ull)p1 | ((ull)sSeq << 32), __ATOMIC_RELAXED, AGT);
      }
      asm volatile("" ::: "memory");

      // out(k-1) from this wave's staged h1(k-1), off the producer path
      if (doPrev && oslot && wq == owave) {
        f16x8 hv = *(const f16x8*)((const char*)myB1 + b_o * BSTR + lane * 16);
        float sd = 0.f;
#pragma unroll
        for (int j = 0; j < 8; ++j) sd += (float)hv[j] * wo[j];
#pragma unroll
        for (int o2 = 1; o2 < 64; o2 <<= 1) sd += __shfl_xor(sd, o2, 64);
        if (lane == 0) {
          int tt = k - 1;
          float val = 0.f;
          if (tt < Lmax_s) val = (tt > Lb_o) ? bo_r : (sd + bo_r);
          out[(((4 * team + b_o) * 24 + s) * 48 + tt) * 5 + o_o] = val;
        }
      }
    }
  }
}

extern "C" void kernel_launch(void* const* d_in, const int* in_sizes, int n_in,
                              void* d_out, int out_size, void* d_ws, size_t ws_size,
                              hipStream_t stream) {
  (void)in_sizes; (void)n_in; (void)out_size; (void)ws_size;
  // Pad LDS to 96KB: forces 1 block/CU so the persistent grid maps 1:1 to CUs.
  int lds_bytes = 98304;
  hipFuncSetAttribute((const void*)rnn_decoder_kernel,
                      hipFuncAttributeMaxDynamicSharedMemorySize, lds_bytes);
  // zero all team exchange regions (seq 0 != any expected seq >= 1)
  hipMemsetAsync(d_ws, 0, 8 * 6144 * 8, stream);
  rnn_decoder_kernel<<<dim3(NB), dim3(NT), lds_bytes, stream>>>(
      (const float*)d_in[0],   // enc_features
      (const float*)d_in[1],   // vector_sketch
      (const int*)d_in[3],     // batch_stroke_len
      (const float*)d_in[4],   // W_sc_ih
      (const float*)d_in[5],   // W_sc_hh
      (const float*)d_in[6],   // b_sc
      (const float*)d_in[7],   // W0_ih
      (const float*)d_in[8],   // W0_hh
      (const float*)d_in[9],   // b0
      (const float*)d_in[10],  // W1_ih
      (const float*)d_in[11],  // W1_hh
      (const float*)d_in[12],  // b1
      (const float*)d_in[13],  // W_out
      (const float*)d_in[14],  // b_out
      (float*)d_out, (float*)d_ws);
}

// Round 14
// 5850.704 us; speedup vs baseline: 1.3888x; 1.3888x over previous
//
#include <hip/hip_runtime.h>

#define NB 256
#define NT 256
#define AGT __HIP_MEMORY_SCOPE_AGENT
#define WGS __HIP_MEMORY_SCOPE_WORKGROUP
typedef unsigned long long ull;
typedef _Float16 f16;
typedef __attribute__((ext_vector_type(8))) _Float16 f16x8;
typedef __attribute__((ext_vector_type(4))) float f32x4;

// B=32, S=24, T=48, hidden 512, gate dim 2048.
// 8 teams x 4 batches (team=w>>5, slot=w&31). Slot owns units 16s..16s+15.
// R14: SPLIT-CHAIN WAVE GROUPS. Waves 0-1 (L0 group) run the h0 chain; waves
// 2-3 (L1 group) run the h1 chain. No __syncthreads in the 49-iter loop; the
// two waves of a group sync via monotonic LDS seq flags (release/acquire).
// L1 reads the L0 group's shared h0 LDS tile (no redundant LLC loads - R13
// lesson; R13's 5e8 bank conflicts came from its stageW write pattern, fixed
// here with lane-consecutive 4B writes).
// Safety: h0T has 4 parities + L0 gates phase j on "own L1 done with T0 of
// phase j-2" (gd flags, >= compare) -> bounds all consumers (P=4 proof).
// h1T keeps 2 parities (L1 groups mutually synced by the h1 chain).
// Exchange: seq-embedded 8B chunks (4B fp16x2 + 4B seq), agent atomics (R12).

#define BSTR 1056

struct __align__(16) SMem {
  unsigned short T0[2][4 * 528];   // L0-staged h0 tiles (by k&1), read by both groups
  unsigned short T1[2][4 * 528];   // L1-staged h1 tiles
  unsigned short Bs[2][4 * 528];   // scene/t0 shared staging
  float Xs[48][4][8];              // stroke's sketch tokens
  float X0[4][8];
  float sS0[16][4][4];             // t0 s0 per [unit][batch][gate]
  float sC0[16][4];                // t0 c0 state handoff
  float sH0[16][4];                // t0 h0 state handoff
  int sLens[2][4];
  int sLmax[2];
  unsigned gFlag[8];               // 0,1: T0 halves staged; 2,3: T1 halves; 4,5: L1 done T0
};

__device__ __forceinline__ float sigm(float x) { return 1.0f / (1.0f + expf(-x)); }
__device__ __forceinline__ unsigned short f16b(float x) {
  union { _Float16 h; unsigned short u; } q; q.h = (_Float16)x; return q.u;
}
__device__ __forceinline__ ull pk4(float a, float b, float c, float d) {
  union { _Float16 h; unsigned short u; } q;
  ull r; q.h = (_Float16)a; r = q.u; q.h = (_Float16)b; r |= (ull)q.u << 16;
  q.h = (_Float16)c; r |= (ull)q.u << 32; q.h = (_Float16)d; r |= (ull)q.u << 48;
  return r;
}
__device__ __forceinline__ ull lda8(const ull* p) {
  return __hip_atomic_load(p, __ATOMIC_RELAXED, AGT);
}

extern "C" __global__ void __launch_bounds__(NT, 1)
rnn_decoder_kernel(const float* __restrict__ enc, const float* __restrict__ sketch,
                   const int* __restrict__ slen,
                   const float* __restrict__ Wsc_ih, const float* __restrict__ Wsc_hh,
                   const float* __restrict__ bsc,
                   const float* __restrict__ W0ih, const float* __restrict__ W0hh,
                   const float* __restrict__ b0,
                   const float* __restrict__ W1ih, const float* __restrict__ W1hh,
                   const float* __restrict__ b1,
                   const float* __restrict__ Wout, const float* __restrict__ bout,
                   float* __restrict__ out, float* __restrict__ ws)
{
  extern __shared__ char smraw[];
  SMem* sm = (SMem*)smraw;
  const int tid = threadIdx.x;
  const int w = blockIdx.x;
  const int team = w >> 5, slot = w & 31;
  const int lane = tid & 63;
  const int wq = tid >> 6;
  const int l15 = lane & 15;
  const int kq = lane >> 4;
  const int my_b = l15 & 3;
  const int my_u = wq * 4 + kq;          // t0/scene-phase unit (old layout)
  const int wid2 = wq & 1;               // wave index within group
  const int uA = 8 * wid2 + kq, uB = uA + 4;  // loop-layout units

  ull* tb = (ull*)ws + (size_t)team * 8192;
  ull* h0T = tb;                         // 4 parities x 1024
  ull* h1T = tb + 4096;                  // 2 parities x 1024
  ull* sHg = tb + 6144;                  // 2 parities x 1024

  auto grow = [&](int r) { return ((r & 3) << 9) + slot * 16 + (r >> 2); };
  auto ldsB = [&](const unsigned short* Bp, int st) -> f16x8 {
    return *(const f16x8*)((const char*)Bp + my_b * BSTR + st * 64 + kq * 16);
  };
  auto mkfrag = [&](const float* q) -> f16x8 {
    float4 u0 = *(const float4*)q, u1 = *(const float4*)(q + 4);
    f16x8 a;
    a[0]=(f16)u0.x; a[1]=(f16)u0.y; a[2]=(f16)u0.z; a[3]=(f16)u0.w;
    a[4]=(f16)u1.x; a[5]=(f16)u1.y; a[6]=(f16)u1.z; a[7]=(f16)u1.w;
    return a;
  };
  auto mfma_gv = [&](const float* W, int stride, int coloff, const unsigned short* Bp, f32x4& acc) {
    const float* rp = W + (size_t)grow(wq * 16 + l15) * stride + coloff;
#pragma unroll
    for (int st = 0; st < 16; ++st)
      acc = __builtin_amdgcn_mfma_f32_16x16x32_f16(mkfrag(rp + st * 32 + kq * 8),
                                                   ldsB(Bp, st), acc, 0, 0, 0);
  };
  auto mfma_gs = [&](const float* W, const unsigned short* Bp, f32x4& acc) {
    const float* rp = W + (size_t)grow(wq * 16 + l15) * 517;
#pragma unroll
    for (int st = 0; st < 16; ++st) {
      const float* q = rp + st * 32 + kq * 8;
      f16x8 a;
#pragma unroll
      for (int j = 0; j < 8; ++j) a[j] = (f16)q[j];
      acc = __builtin_amdgcn_mfma_f32_16x16x32_f16(a, ldsB(Bp, st), acc, 0, 0, 0);
    }
  };

  // ---- block-wide staging (scene/t0), R12-proven ----
  auto stage4 = [&](const ull* s0, unsigned e0, unsigned short* Bp) {
    const ull* pA = s0 + 2 * tid;
    const ull* pB = pA + 1;
    const ull* pC = s0 + 512 + 2 * tid;
    const ull* pD = pC + 1;
    ull a = lda8(pA), b = lda8(pB), c = lda8(pC), d = lda8(pD);
    int spins = 0;
    while ((((unsigned)(a >> 32) ^ e0) | ((unsigned)(b >> 32) ^ e0) |
            ((unsigned)(c >> 32) ^ e0) | ((unsigned)(d >> 32) ^ e0)) != 0) {
      if (++spins > 60000) break;
      if (spins > 16) __builtin_amdgcn_s_sleep(1);
      if ((unsigned)(a >> 32) != e0) a = lda8(pA);
      if ((unsigned)(b >> 32) != e0) b = lda8(pB);
      if ((unsigned)(c >> 32) != e0) c = lda8(pC);
      if ((unsigned)(d >> 32) != e0) d = lda8(pD);
    }
    int bb2 = tid >> 7, up = (2 * tid) & 255;
    *(ull*)((char*)Bp + bb2 * BSTR + up * 4) = (ull)(unsigned)a | ((ull)(unsigned)b << 32);
    int t2 = tid + 256, bb3 = t2 >> 7, up2 = (2 * t2) & 255;
    *(ull*)((char*)Bp + bb3 * BSTR + up2 * 4) = (ull)(unsigned)c | ((ull)(unsigned)d << 32);
  };

  // ---- per-wave half-tile staging: lane covers chunks wid2*512 + lane + 64i ----
  // LDS writes: 4B, lane-consecutive -> conflict-free (R13 bug fixed).
  auto stageH = [&](const ull* src, unsigned e0, unsigned short* T) {
    const ull* p = src + wid2 * 512 + lane;
    ull v[8];
#pragma unroll
    for (int i = 0; i < 8; ++i) v[i] = lda8(p + 64 * i);
    int spins = 0;
    for (;;) {
      unsigned bad = 0;
#pragma unroll
      for (int i = 0; i < 8; ++i) bad |= ((unsigned)(v[i] >> 32)) ^ e0;
      if (!bad) break;
      if (++spins > 60000) break;
      if (spins > 8) __builtin_amdgcn_s_sleep(1);
#pragma unroll
      for (int i = 0; i < 8; ++i)
        if ((unsigned)(v[i] >> 32) != e0) v[i] = lda8(p + 64 * i);
    }
#pragma unroll
    for (int i = 0; i < 8; ++i) {
      int c = wid2 * 512 + lane + 64 * i;
      *(unsigned*)((char*)T + (c >> 8) * BSTR + (c & 255) * 4) = (unsigned)v[i];
    }
  };
  auto fstore = [&](int idx, unsigned v) {
    __hip_atomic_store(&sm->gFlag[idx], v, __ATOMIC_RELEASE, WGS);
  };
  auto fwait = [&](int idx, unsigned v) {
    int spins = 0;
    while (__hip_atomic_load(&sm->gFlag[idx], __ATOMIC_ACQUIRE, WGS) < v) {
      if (++spins > 200000) break;
      if (spins > 8) __builtin_amdgcn_s_sleep(1);
    }
  };

  // ---------- init ----------
  if (tid < 8) sm->gFlag[tid] = 0u;

  // loop weights: L0 waves -> W0hh (wA); L1 waves -> W1ih (wA) + W1hh (wB).
  f16x8 wA[32], wB[32];
  {
    const float* SA = (wq < 2) ? W0hh : W1ih;
#pragma unroll
    for (int t2 = 0; t2 < 2; ++t2) {
      const float* rp = SA + (size_t)grow(32 * wid2 + 16 * t2 + l15) * 512;
#pragma unroll
      for (int st = 0; st < 16; ++st) wA[t2 * 16 + st] = mkfrag(rp + st * 32 + kq * 8);
    }
    if (wq >= 2) {
#pragma unroll
      for (int t2 = 0; t2 < 2; ++t2) {
        const float* rp = W1hh + (size_t)grow(32 * wid2 + 16 * t2 + l15) * 512;
#pragma unroll
        for (int st = 0; st < 16; ++st) wB[t2 * 16 + st] = mkfrag(rp + st * 32 + kq * 8);
      }
    }
  }
  // loop cell constants (2 units per lane)
  const int guA = slot * 16 + uA, guB = slot * 16 + uB;
  float cbA[4], cbB[4], cwA[4][5], cwB[4][5];
  if (wq < 2) {
#pragma unroll
    for (int gi = 0; gi < 4; ++gi) {
      cbA[gi] = b0[gi * 512 + guA]; cbB[gi] = b0[gi * 512 + guB];
#pragma unroll
      for (int j = 0; j < 5; ++j) {
        cwA[gi][j] = W0ih[(size_t)(gi * 512 + guA) * 517 + 512 + j];
        cwB[gi][j] = W0ih[(size_t)(gi * 512 + guB) * 517 + 512 + j];
      }
    }
  } else {
#pragma unroll
    for (int gi = 0; gi < 4; ++gi) {
      cbA[gi] = b1[gi * 512 + guA]; cbB[gi] = b1[gi * 512 + guB];
    }
  }
  float cbsc[4];
#pragma unroll
  for (int gi = 0; gi < 4; ++gi) cbsc[gi] = bsc[gi * 512 + slot * 16 + my_u];
  const int b_o = slot / 5, o_o = slot % 5;
  const bool oslot = (slot < 20);
  float wo[8]; float bo_r = 0.f;
  if (oslot) {
    bo_r = bout[o_o];
#pragma unroll
    for (int j = 0; j < 8; ++j) wo[j] = Wout[o_o * 512 + lane * 8 + j];
  }

  // e0reg = Wsc_ih[:, :512] @ enc
  f32x4 e0reg = {0.f, 0.f, 0.f, 0.f};
  {
    int b2 = tid >> 6, c8 = tid & 63;
    const float* q = enc + (size_t)(4 * team + b2) * 512 + c8 * 8;
    float4 u0 = *(const float4*)q, u1 = *(const float4*)(q + 4);
    unsigned short* Bp = &sm->Bs[0][0];
    *(ull*)((char*)Bp + b2 * BSTR + c8 * 16) = pk4(u0.x, u0.y, u0.z, u0.w);
    *(ull*)((char*)Bp + b2 * BSTR + c8 * 16 + 8) = pk4(u1.x, u1.y, u1.z, u1.w);
    __syncthreads();
    mfma_gv(Wsc_ih, 1024, 0, Bp, e0reg);
  }

  float o_csc = 0.f;

  for (int s = 0; s < 24; ++s) {
    const unsigned base = 51u * (unsigned)s;

    // ================= scene phase (block-wide) =================
    {
      int lv = (tid < 32) ? slen[tid * 24 + s] : 0;
      if (tid < 64) {
#pragma unroll
        for (int o2 = 1; o2 < 64; o2 <<= 1) lv = max(lv, __shfl_xor(lv, o2, 64));
        if (tid == 0) sm->sLmax[s & 1] = lv;
      }
      if (tid < 4) sm->sLens[s & 1][tid] = slen[(4 * team + tid) * 24 + s];
    }
    {
      unsigned short* Bp0 = &sm->Bs[0][0];
      unsigned short* Bp1 = &sm->Bs[1][0];
      if (s > 0) {
        stage4(h1T, base, Bp0);                              // final h1 (parity 0)
        stage4(sHg + ((s - 1) & 1) * 1024, base - 50u, Bp1); // scene_h(s-1)
      }
      __syncthreads();
      f32x4 asc = {0.f, 0.f, 0.f, 0.f};
      if (s > 0) {
        mfma_gv(Wsc_ih, 1024, 512, Bp0, asc);
        mfma_gv(Wsc_hh, 512, 0, Bp1, asc);
      }
      float g[4];
#pragma unroll
      for (int gi = 0; gi < 4; ++gi) g[gi] = e0reg[gi] + cbsc[gi] + asc[gi];
      float c = sigm(g[1]) * o_csc + sigm(g[0]) * tanhf(g[2]);
      float h = sigm(g[3]) * tanhf(c);
      o_csc = c;
      float hhi = __shfl_down(h, 16, 64);
      if (((kq & 1) == 0) && (l15 < 4)) {
        int chunk = my_b * 256 + slot * 8 + wq * 2 + (kq >> 1);
        __hip_atomic_store(&sHg[(s & 1) * 1024 + chunk],
                           (ull)((unsigned)f16b(h) | ((unsigned)f16b(hhi) << 16)) |
                           ((ull)(base + 1u) << 32), __ATOMIC_RELAXED, AGT);
      }
    }

    // ================= t0 pre-step (block-wide) =================
    {
      __syncthreads();
      unsigned short* Bp0 = &sm->Bs[0][0];
      if (tid < 4) {
        float xv[5];
        if (s == 0) { xv[0]=0.f; xv[1]=0.f; xv[2]=1.f; xv[3]=0.f; xv[4]=0.f; }
        else {
          int bgl = 4 * team + tid;
          int lp = slen[bgl * 24 + (s - 1)];
          int last = min(max(lp - 1, 0), 47);
          const float* q = sketch + ((bgl * 24 + (s - 1)) * 48 + last) * 5;
#pragma unroll
          for (int j = 0; j < 5; ++j) xv[j] = q[j];
        }
#pragma unroll
        for (int j = 0; j < 5; ++j) sm->X0[tid][j] = xv[j];
      }
      for (int e = tid; e < 960; e += NT) {
        int k2 = e / 20, r2 = e % 20, b2 = r2 / 5, j2 = r2 % 5;
        sm->Xs[k2][b2][j2] = sketch[(((4 * team + b2) * 24 + s) * 48 + k2) * 5 + j2];
      }
      stage4(sHg + (s & 1) * 1024, base + 1u, Bp0);
      __syncthreads();
      f32x4 s0reg = {0.f, 0.f, 0.f, 0.f};
      mfma_gs(W0ih, Bp0, s0reg);
      float tb0[4], twx[4][5];
#pragma unroll
      for (int gi = 0; gi < 4; ++gi) {
        int gr = gi * 512 + slot * 16 + my_u;
        tb0[gi] = b0[gr];
#pragma unroll
        for (int j = 0; j < 5; ++j) twx[gi][j] = W0ih[(size_t)gr * 517 + 512 + j];
      }
      float g[4];
#pragma unroll
      for (int gi = 0; gi < 4; ++gi) {
        float xd = 0.f;
#pragma unroll
        for (int j = 0; j < 5; ++j) xd += twx[gi][j] * sm->X0[my_b][j];
        g[gi] = s0reg[gi] + tb0[gi] + xd;
      }
      float c = sigm(g[1]) * 0.f + sigm(g[0]) * tanhf(g[2]);
      float h = sigm(g[3]) * tanhf(c);
      if (l15 < 4) {
        sm->sC0[my_u][my_b] = c;
        sm->sH0[my_u][my_b] = h;
        sm->sS0[my_u][my_b][0] = s0reg[0]; sm->sS0[my_u][my_b][1] = s0reg[1];
        sm->sS0[my_u][my_b][2] = s0reg[2]; sm->sS0[my_u][my_b][3] = s0reg[3];
      }
      float hhi = __shfl_down(h, 16, 64);
      if (((kq & 1) == 0) && (l15 < 4)) {
        int chunk = my_b * 256 + slot * 8 + wq * 2 + (kq >> 1);
        __hip_atomic_store(&h0T[chunk],
                           (ull)((unsigned)f16b(h) | ((unsigned)f16b(hhi) << 16)) |
                           ((ull)(base + 2u) << 32), __ATOMIC_RELAXED, AGT);
      }
      __syncthreads();                      // Xs/sS0/sC0/sH0/lens visible to loop
    }

    const int Lb = sm->sLens[s & 1][my_b];

    // ============ split-chain loop: NO block syncs ============
    if (wq < 2) {
      // ---------------- L0 group: h0 chain ----------------
      float cA = sm->sC0[uA][my_b], hA = sm->sH0[uA][my_b];
      float cB = sm->sC0[uB][my_b], hB = sm->sH0[uB][my_b];
      float s0A0 = sm->sS0[uA][my_b][0], s0A1 = sm->sS0[uA][my_b][1],
            s0A2 = sm->sS0[uA][my_b][2], s0A3 = sm->sS0[uA][my_b][3];
      float s0B0 = sm->sS0[uB][my_b][0], s0B1 = sm->sS0[uB][my_b][1],
            s0B2 = sm->sS0[uB][my_b][2], s0B3 = sm->sS0[uB][my_b][3];
      for (int k = 0; k <= 48; ++k) {
        const unsigned eSeq = base + 2u + (unsigned)k, sSeq = eSeq + 1u;
        if (k >= 2) { fwait(4, base + (unsigned)k); fwait(5, base + (unsigned)k); }
        stageH(h0T + (size_t)(k & 3) * 1024, eSeq, sm->T0[k & 1]);
        asm volatile("s_waitcnt lgkmcnt(0)" ::: "memory");
        fstore(wid2, eSeq);
        fwait(wid2 ^ 1, eSeq);
        __builtin_amdgcn_sched_barrier(0);
        if (k < 48) {
          f32x4 aA = {0.f,0.f,0.f,0.f}, aB = {0.f,0.f,0.f,0.f};
#pragma unroll
          for (int st = 0; st < 16; ++st) {
            f16x8 bb = ldsB(sm->T0[k & 1], st);
            aA = __builtin_amdgcn_mfma_f32_16x16x32_f16(wA[st], bb, aA, 0, 0, 0);
            aB = __builtin_amdgcn_mfma_f32_16x16x32_f16(wA[16 + st], bb, aB, 0, 0, 0);
          }
          if ((k + 1) <= Lb) {
            float xd[4];
#pragma unroll
            for (int gi = 0; gi < 4; ++gi) {
              xd[gi] = 0.f;
#pragma unroll
              for (int j = 0; j < 5; ++j) xd[gi] += cwA[gi][j] * sm->Xs[k][my_b][j];
            }
            float g0 = aA[0] + s0A0 + cbA[0] + xd[0];
            float g1 = aA[1] + s0A1 + cbA[1] + xd[1];
            float g2 = aA[2] + s0A2 + cbA[2] + xd[2];
            float g3 = aA[3] + s0A3 + cbA[3] + xd[3];
            cA = sigm(g1) * cA + sigm(g0) * tanhf(g2);
            hA = sigm(g3) * tanhf(cA);
#pragma unroll
            for (int gi = 0; gi < 4; ++gi) {
              xd[gi] = 0.f;
#pragma unroll
              for (int j = 0; j < 5; ++j) xd[gi] += cwB[gi][j] * sm->Xs[k][my_b][j];
            }
            g0 = aB[0] + s0B0 + cbB[0] + xd[0];
            g1 = aB[1] + s0B1 + cbB[1] + xd[1];
            g2 = aB[2] + s0B2 + cbB[2] + xd[2];
            g3 = aB[3] + s0B3 + cbB[3] + xd[3];
            cB = sigm(g1) * cB + sigm(g0) * tanhf(g2);
            hB = sigm(g3) * tanhf(cB);
          }
          float hA2 = __shfl_down(hA, 16, 64);
          float hB2 = __shfl_down(hB, 16, 64);
          if (((kq & 1) == 0) && (l15 < 4)) {
            int cbase = my_b * 256 + slot * 8 + 4 * wid2 + (kq >> 1);
            size_t pb = (size_t)((k + 1) & 3) * 1024;
            __hip_atomic_store(&h0T[pb + cbase],
                               (ull)((unsigned)f16b(hA) | ((unsigned)f16b(hA2) << 16)) |
                               ((ull)sSeq << 32), __ATOMIC_RELAXED, AGT);
            __hip_atomic_store(&h0T[pb + cbase + 2],
                               (ull)((unsigned)f16b(hB) | ((unsigned)f16b(hB2) << 16)) |
                               ((ull)sSeq << 32), __ATOMIC_RELAXED, AGT);
          }
        }
      }
    } else {
      // ---------------- L1 group: h1 chain ----------------
      const int Lmax_s = sm->sLmax[s & 1];
      const int Lb_o = sm->sLens[s & 1][oslot ? b_o : 0];
      float cA = 0.f, hA = 0.f, cB = 0.f, hB = 0.f;
      for (int k = 0; k <= 48; ++k) {
        const unsigned eSeq = base + 2u + (unsigned)k, sSeq = eSeq + 1u;
        const bool doPrev = (k > 0);
        if (doPrev) {
          stageH(h1T + (size_t)((k - 1) & 1) * 1024, eSeq, sm->T1[k & 1]);
          asm volatile("s_waitcnt lgkmcnt(0)" ::: "memory");
          fstore(2 + wid2, eSeq);
        }
        fwait(0, eSeq); fwait(1, eSeq);      // T0 (h0(k)) staged by L0 group
        __builtin_amdgcn_sched_barrier(0);
        f32x4 aA = {0.f,0.f,0.f,0.f}, aB = {0.f,0.f,0.f,0.f};
#pragma unroll
        for (int st = 0; st < 16; ++st) {
          f16x8 bb = ldsB(sm->T0[k & 1], st);
          aA = __builtin_amdgcn_mfma_f32_16x16x32_f16(wA[st], bb, aA, 0, 0, 0);
          aB = __builtin_amdgcn_mfma_f32_16x16x32_f16(wA[16 + st], bb, aB, 0, 0, 0);
        }
        fstore(4 + wid2, eSeq);              // done reading T0[k&1]
        if (doPrev) {
          fwait(2 + (wid2 ^ 1), eSeq);
          __builtin_amdgcn_sched_barrier(0);
#pragma unroll
          for (int st = 0; st < 16; ++st) {
            f16x8 bb = ldsB(sm->T1[k & 1], st);
            aA = __builtin_amdgcn_mfma_f32_16x16x32_f16(wB[st], bb, aA, 0, 0, 0);
            aB = __builtin_amdgcn_mfma_f32_16x16x32_f16(wB[16 + st], bb, aB, 0, 0, 0);
          }
        }
        if (k <= Lb) {
          float g0 = aA[0] + cbA[0], g1 = aA[1] + cbA[1],
                g2 = aA[2] + cbA[2], g3 = aA[3] + cbA[3];
          cA = sigm(g1) * cA + sigm(g0) * tanhf(g2);
          hA = sigm(g3) * tanhf(cA);
          g0 = aB[0] + cbB[0]; g1 = aB[1] + cbB[1];
          g2 = aB[2] + cbB[2]; g3 = aB[3] + cbB[3];
          cB = sigm(g1) * cB + sigm(g0) * tanhf(g2);
          hB = sigm(g3) * tanhf(cB);
        }
        float hA2 = __shfl_down(hA, 16, 64);
        float hB2 = __shfl_down(hB, 16, 64);
        if (((kq & 1) == 0) && (l15 < 4)) {
          int cbase = my_b * 256 + slot * 8 + 4 * wid2 + (kq >> 1);
          size_t pb = (size_t)(k & 1) * 1024;
          __hip_atomic_store(&h1T[pb + cbase],
                             (ull)((unsigned)f16b(hA) | ((unsigned)f16b(hA2) << 16)) |
                             ((ull)sSeq << 32), __ATOMIC_RELAXED, AGT);
          __hip_atomic_store(&h1T[pb + cbase + 2],
                             (ull)((unsigned)f16b(hB) | ((unsigned)f16b(hB2) << 16)) |
                             ((ull)sSeq << 32), __ATOMIC_RELAXED, AGT);
        }
        if (doPrev && oslot && wq == 2) {    // out(k-1) from staged h1(k-1)
          f16x8 hv = *(const f16x8*)((const char*)sm->T1[k & 1] + b_o * BSTR + lane * 16);
          float sd = 0.f;
#pragma unroll
          for (int j = 0; j < 8; ++j) sd += (float)hv[j] * wo[j];
#pragma unroll
          for (int o2 = 1; o2 < 64; o2 <<= 1) sd += __shfl_xor(sd, o2, 64);
          if (lane == 0) {
            int tt = k - 1;
            float val = 0.f;
            if (tt < Lmax_s) val = (tt > Lb_o) ? bo_r : (sd + bo_r);
            out[(((4 * team + b_o) * 24 + s) * 48 + tt) * 5 + o_o] = val;
          }
        }
      }
    }
    __syncthreads();
  }
}

extern "C" void kernel_launch(void* const* d_in, const int* in_sizes, int n_in,
                              void* d_out, int out_size, void* d_ws, size_t ws_size,
                              hipStream_t stream) {
  (void)in_sizes; (void)n_in; (void)out_size; (void)ws_size;
  int lds_bytes = 98304;   // force 1 block/CU
  hipFuncSetAttribute((const void*)rnn_decoder_kernel,
                      hipFuncAttributeMaxDynamicSharedMemorySize, lds_bytes);
  // zero all team exchange regions: 8 teams x 8192 ull x 8B = 512KB
  hipMemsetAsync(d_ws, 0, 524288, stream);
  rnn_decoder_kernel<<<dim3(NB), dim3(NT), lds_bytes, stream>>>(
      (const float*)d_in[0],   // enc_features
      (const float*)d_in[1],   // vector_sketch
      (const int*)d_in[3],     // batch_stroke_len
      (const float*)d_in[4],   // W_sc_ih
      (const float*)d_in[5],   // W_sc_hh
      (const float*)d_in[6],   // b_sc
      (const float*)d_in[7],   // W0_ih
      (const float*)d_in[8],   // W0_hh
      (const float*)d_in[9],   // b0
      (const float*)d_in[10],  // W1_ih
      (const float*)d_in[11],  // W1_hh
      (const float*)d_in[12],  // b1
      (const float*)d_in[13],  // W_out
      (const float*)d_in[14],  // b_out
      (float*)d_out, (float*)d_ws);
}

// Round 16
// 4070.385 us; speedup vs baseline: 1.9962x; 1.4374x over previous
//
#include <hip/hip_runtime.h>

#define NB 256
#define NT 256
#define AGT __HIP_MEMORY_SCOPE_AGENT
typedef unsigned long long ull;
typedef _Float16 f16;
typedef __attribute__((ext_vector_type(8))) _Float16 f16x8;
typedef __attribute__((ext_vector_type(4))) float f32x4;

// B=32, S=24, T=48, hidden 512, gate dim 2048.
// 8 teams x 4 batches (team=w>>5, slot=w&31). Slot owns units 16s..16s+15.
// GATE-MAJOR row map grow(r) = (r&3)*512 + slot*16 + (r>>2): per-lane register
// cell math in all waves. All 3 recurrent weight matrices in registers as MFMA
// A-fragments. B tiles in LDS, 1056B row stride (2-way = free).
// R16 = R12 verbatim (best verified: 4.06ms). Split-wait skeleton; exchange
// via agent-scope relaxed atomics; seq-embedded 8B chunks (4B fp16x2 + 4B
// seq) with per-chunk retry. Session post-mortem: remaining time is the
// serialized cross-CU communication latency of 1224 phases (2 discoveries
// x ~1.2us each + ~0.9us busy); prefetch timing (R10/R11), wave decoupling
// (R13), split-chain groups (R14), and sub-LLC sc0 exchange (R5/R15) were
// all tried and regressed or were falsified.

#define BSTR 1056   // B-tile row stride in bytes (528 shorts)

struct __align__(16) SMem {
  unsigned short Bt[2][2][4 * 528]; // [pp][0=h0-src,1=h1-src][4 rows x 528]
  float X[2][4][8];                 // x_t, double-buffered by pp
  int sLens[2][4];
  int sLmax[2];
};

__device__ __forceinline__ float sigm(float x) { return 1.0f / (1.0f + expf(-x)); }
__device__ __forceinline__ unsigned short f16b(float x) {
  union { _Float16 h; unsigned short u; } q; q.h = (_Float16)x; return q.u;
}
__device__ __forceinline__ ull pk4(float a, float b, float c, float d) {
  union { _Float16 h; unsigned short u; } q;
  ull r; q.h = (_Float16)a; r = q.u; q.h = (_Float16)b; r |= (ull)q.u << 16;
  q.h = (_Float16)c; r |= (ull)q.u << 32; q.h = (_Float16)d; r |= (ull)q.u << 48;
  return r;
}
__device__ __forceinline__ ull lda8(const ull* p) {
  return __hip_atomic_load(p, __ATOMIC_RELAXED, AGT);
}

extern "C" __global__ void __launch_bounds__(NT, 1)
rnn_decoder_kernel(const float* __restrict__ enc, const float* __restrict__ sketch,
                   const int* __restrict__ slen,
                   const float* __restrict__ Wsc_ih, const float* __restrict__ Wsc_hh,
                   const float* __restrict__ bsc,
                   const float* __restrict__ W0ih, const float* __restrict__ W0hh,
                   const float* __restrict__ b0,
                   const float* __restrict__ W1ih, const float* __restrict__ W1hh,
                   const float* __restrict__ b1,
                   const float* __restrict__ Wout, const float* __restrict__ bout,
                   float* __restrict__ out, float* __restrict__ ws)
{
  extern __shared__ char smraw[];
  SMem* sm = (SMem*)smraw;
  const int tid = threadIdx.x;
  const int w = blockIdx.x;
  const int team = w >> 5, slot = w & 31;
  const int lane = tid & 63;
  const int wq = tid >> 6;
  const int l15 = lane & 15;
  const int kq = lane >> 4;
  const int my_b = l15 & 3;
  const int my_u = wq * 4 + kq;

  ull* tb = (ull*)ws + (size_t)team * 6144;
  ull* h0T = tb;
  ull* h1T = tb + 2048;
  ull* sHg = tb + 4096;

  auto grow = [&](int r) { return ((r & 3) << 9) + slot * 16 + (r >> 2); };

  auto ldsB = [&](const unsigned short* Bp, int st) -> f16x8 {
    return *(const f16x8*)((const char*)Bp + my_b * BSTR + st * 64 + kq * 16);
  };
  auto mfma_gv = [&](const float* W, int stride, int coloff, const unsigned short* Bp, f32x4& acc) {
    const float* rp = W + (size_t)grow(wq * 16 + l15) * stride + coloff;
#pragma unroll
    for (int st = 0; st < 16; ++st) {
      const float* q = rp + st * 32 + kq * 8;
      float4 u0 = *(const float4*)q, u1 = *(const float4*)(q + 4);
      f16x8 a;
      a[0] = (f16)u0.x; a[1] = (f16)u0.y; a[2] = (f16)u0.z; a[3] = (f16)u0.w;
      a[4] = (f16)u1.x; a[5] = (f16)u1.y; a[6] = (f16)u1.z; a[7] = (f16)u1.w;
      acc = __builtin_amdgcn_mfma_f32_16x16x32_f16(a, ldsB(Bp, st), acc, 0, 0, 0);
    }
  };
  auto mfma_gs = [&](const float* W, const unsigned short* Bp, f32x4& acc) {
    const float* rp = W + (size_t)grow(wq * 16 + l15) * 517;
#pragma unroll
    for (int st = 0; st < 16; ++st) {
      const float* q = rp + st * 32 + kq * 8;
      f16x8 a;
#pragma unroll
      for (int j = 0; j < 8; ++j) a[j] = (f16)q[j];
      acc = __builtin_amdgcn_mfma_f32_16x16x32_f16(a, ldsB(Bp, st), acc, 0, 0, 0);
    }
  };

  // ---------- seq-embedded staging (agent-scope compiler atomics) ----------
  // tile chunk layout: chunk i: batch=i>>8, unit-pair=i&255 (8B = pay|seq).
  // thread tid handles chunk pairs (2tid,2tid+1) and (512+2tid, 513+2tid).
  auto stage4 = [&](const ull* s0, unsigned e0, unsigned short* Bp) {
    const ull* pA = s0 + 2 * tid;
    const ull* pB = pA + 1;
    const ull* pC = s0 + 512 + 2 * tid;
    const ull* pD = pC + 1;
    ull a = lda8(pA), b = lda8(pB), c = lda8(pC), d = lda8(pD);
    int spins = 0;
    while ((((unsigned)(a >> 32) ^ e0) | ((unsigned)(b >> 32) ^ e0) |
            ((unsigned)(c >> 32) ^ e0) | ((unsigned)(d >> 32) ^ e0)) != 0) {
      if (++spins > 40000) break;          // bailout: garbage > hang
      if (spins > 16) __builtin_amdgcn_s_sleep(1);
      if ((unsigned)(a >> 32) != e0) a = lda8(pA);
      if ((unsigned)(b >> 32) != e0) b = lda8(pB);
      if ((unsigned)(c >> 32) != e0) c = lda8(pC);
      if ((unsigned)(d >> 32) != e0) d = lda8(pD);
    }
    {
      int bb2 = tid >> 7, up = (2 * tid) & 255;
      *(ull*)((char*)Bp + bb2 * BSTR + up * 4) =
          (ull)(unsigned)a | ((ull)(unsigned)b << 32);
      int t2 = tid + 256;
      int bb3 = t2 >> 7, up2 = (2 * t2) & 255;
      *(ull*)((char*)Bp + bb3 * BSTR + up2 * 4) =
          (ull)(unsigned)c | ((ull)(unsigned)d << 32);
    }
  };

  // ---------- init: ALL recurrent weights into registers ----------
  f16x8 w0hh[16], w1ih[16], whh[16];
  {
    const float* r0 = W0hh + (size_t)grow(wq * 16 + l15) * 512;
    const float* r1 = W1ih + (size_t)grow(wq * 16 + l15) * 512;
    const float* r2 = W1hh + (size_t)grow(wq * 16 + l15) * 512;
#pragma unroll
    for (int st = 0; st < 16; ++st) {
      const int o = st * 32 + kq * 8;
      float4 u0, u1;
      f16x8 a;
      u0 = *(const float4*)(r0 + o); u1 = *(const float4*)(r0 + o + 4);
      a[0] = (f16)u0.x; a[1] = (f16)u0.y; a[2] = (f16)u0.z; a[3] = (f16)u0.w;
      a[4] = (f16)u1.x; a[5] = (f16)u1.y; a[6] = (f16)u1.z; a[7] = (f16)u1.w;
      w0hh[st] = a;
      u0 = *(const float4*)(r1 + o); u1 = *(const float4*)(r1 + o + 4);
      a[0] = (f16)u0.x; a[1] = (f16)u0.y; a[2] = (f16)u0.z; a[3] = (f16)u0.w;
      a[4] = (f16)u1.x; a[5] = (f16)u1.y; a[6] = (f16)u1.z; a[7] = (f16)u1.w;
      w1ih[st] = a;
      u0 = *(const float4*)(r2 + o); u1 = *(const float4*)(r2 + o + 4);
      a[0] = (f16)u0.x; a[1] = (f16)u0.y; a[2] = (f16)u0.z; a[3] = (f16)u0.w;
      a[4] = (f16)u1.x; a[5] = (f16)u1.y; a[6] = (f16)u1.z; a[7] = (f16)u1.w;
      whh[st] = a;
    }
  }
  float cb0[4], cb1[4], cbsc[4], cwx[4][5];
  {
    int gu = slot * 16 + my_u;
#pragma unroll
    for (int gi = 0; gi < 4; ++gi) {
      int gr = gi * 512 + gu;
      cb0[gi] = b0[gr]; cb1[gi] = b1[gr]; cbsc[gi] = bsc[gr];
#pragma unroll
      for (int j = 0; j < 5; ++j) cwx[gi][j] = W0ih[(size_t)gr * 517 + 512 + j];
    }
  }
  const int b_o = slot / 5, o_o = slot % 5;
  const bool oslot = (slot < 20);
  float wo[8]; float bo_r = 0.f;
  if (oslot && tid < 64) {
    bo_r = bout[o_o];
#pragma unroll
    for (int j = 0; j < 8; ++j) wo[j] = Wout[o_o * 512 + lane * 8 + j];
  }

  // e0reg = Wsc_ih[:, :512] @ enc  -> per-lane f32x4
  f32x4 e0reg = {0.f, 0.f, 0.f, 0.f};
  {
    int b2 = tid >> 6, c8 = tid & 63;
    const float* q = enc + (size_t)(4 * team + b2) * 512 + c8 * 8;
    float4 u0 = *(const float4*)q, u1 = *(const float4*)(q + 4);
    unsigned short* Bp = &sm->Bt[0][0][0];
    *(ull*)((char*)Bp + b2 * BSTR + c8 * 16) = pk4(u0.x, u0.y, u0.z, u0.w);
    *(ull*)((char*)Bp + b2 * BSTR + c8 * 16 + 8) = pk4(u1.x, u1.y, u1.z, u1.w);
    __syncthreads();
    mfma_gv(Wsc_ih, 1024, 0, Bp, e0reg);
  }

  float o_csc = 0.f, o_c0 = 0.f, o_h0 = 0.f, o_c1 = 0.f, o_h1 = 0.f;
  int pp = 0;

  for (int s = 0; s < 24; ++s) {
    const unsigned base = 51u * (unsigned)s;

    // ================= scene phase =================
    pp ^= 1;
    {
      int lv = (tid < 32) ? slen[tid * 24 + s] : 0;
      if (tid < 64) {
#pragma unroll
        for (int o2 = 1; o2 < 64; o2 <<= 1) lv = max(lv, __shfl_xor(lv, o2, 64));
        if (tid == 0) sm->sLmax[s & 1] = lv;
      }
      if (tid < 4) sm->sLens[s & 1][tid] = slen[(4 * team + tid) * 24 + s];
    }
    {
      unsigned short* Bp0 = &sm->Bt[pp][0][0];
      unsigned short* Bp1 = &sm->Bt[pp][1][0];
      if (s > 0) {
        stage4(h1T, base, Bp0);
        stage4(sHg + ((s - 1) & 1) * 1024, base - 50u, Bp1);
      }
      __syncthreads();
      f32x4 asc = {0.f, 0.f, 0.f, 0.f};
      if (s > 0) {
        mfma_gv(Wsc_ih, 1024, 512, Bp0, asc);   // prev_tok = final h1
        mfma_gv(Wsc_hh, 512, 0, Bp1, asc);      // scene_h(s-1)
      }
      float g[4];
#pragma unroll
      for (int gi = 0; gi < 4; ++gi) g[gi] = e0reg[gi] + cbsc[gi] + asc[gi];
      float c = sigm(g[1]) * o_csc + sigm(g[0]) * tanhf(g[2]);
      float h = sigm(g[3]) * tanhf(c);
      o_csc = c;
      o_c0 = o_h0 = o_c1 = o_h1 = 0.f;
      float hhi = __shfl_down(h, 16, 64);
      if (((kq & 1) == 0) && (l15 < 4)) {
        int chunk = my_b * 256 + slot * 8 + wq * 2 + (kq >> 1);
        __hip_atomic_store(&sHg[(s & 1) * 1024 + chunk],
                           (ull)((unsigned)f16b(h) | ((unsigned)f16b(hhi) << 16)) |
                           ((ull)(base + 1u) << 32), __ATOMIC_RELAXED, AGT);
      }
    }

    // ================= t0 pre-step: h0(0) =================
    pp ^= 1;
    f32x4 s0reg = {0.f, 0.f, 0.f, 0.f};
    {
      unsigned short* Bp0 = &sm->Bt[pp][0][0];
      if (tid < 4) {
        float xv[5];
        if (s == 0) { xv[0] = 0.f; xv[1] = 0.f; xv[2] = 1.f; xv[3] = 0.f; xv[4] = 0.f; }
        else {
          int bgl = 4 * team + tid;
          int lp = slen[bgl * 24 + (s - 1)];
          int last = min(max(lp - 1, 0), 47);
          const float* q = sketch + ((bgl * 24 + (s - 1)) * 48 + last) * 5;
#pragma unroll
          for (int j = 0; j < 5; ++j) xv[j] = q[j];
        }
#pragma unroll
        for (int j = 0; j < 5; ++j) sm->X[pp][tid][j] = xv[j];
      }
      stage4(sHg + (s & 1) * 1024, base + 1u, Bp0);
      __syncthreads();
      mfma_gs(W0ih, Bp0, s0reg);
      float g[4];
#pragma unroll
      for (int gi = 0; gi < 4; ++gi) {
        float xd = 0.f;
#pragma unroll
        for (int j = 0; j < 5; ++j) xd += cwx[gi][j] * sm->X[pp][my_b][j];
        g[gi] = s0reg[gi] + cb0[gi] + xd;
      }
      float c = sigm(g[1]) * o_c0 + sigm(g[0]) * tanhf(g[2]);
      o_c0 = c; o_h0 = sigm(g[3]) * tanhf(c);
      float hhi = __shfl_down(o_h0, 16, 64);
      if (((kq & 1) == 0) && (l15 < 4)) {
        int chunk = my_b * 256 + slot * 8 + wq * 2 + (kq >> 1);
        __hip_atomic_store(&h0T[chunk],
                           (ull)((unsigned)f16b(o_h0) | ((unsigned)f16b(hhi) << 16)) |
                           ((ull)(base + 2u) << 32), __ATOMIC_RELAXED, AGT);
      }
    }

    // ================= fused iterations (split-wait pipeline) =================
    for (int k = 0; k <= 48; ++k) {
      const bool doL0 = (k < 48), doPrev = (k > 0);
      const unsigned eSeq = base + 2u + (unsigned)k, sSeq = eSeq + 1u;
      pp ^= 1;
      unsigned short* B0p = &sm->Bt[pp][0][0];
      unsigned short* B1p = &sm->Bt[pp][1][0];
      if (doL0 && tid < 4) {
        const float* q = sketch + (((4 * team + tid) * 24 + s) * 48 + k) * 5;
#pragma unroll
        for (int j = 0; j < 5; ++j) sm->X[pp][tid][j] = q[j];
      }
      // ---- stage 1: h0 tile, B0-dependent MFMAs, L0 cell, EARLY h0 store ----
      stage4(h0T + (k & 1) * 1024, eSeq, B0p);
      __syncthreads();

      f32x4 a0 = {0.f, 0.f, 0.f, 0.f}, a1 = {0.f, 0.f, 0.f, 0.f};
#pragma unroll
      for (int st = 0; st < 16; ++st) {
        f16x8 bb = ldsB(B0p, st);
        if (doL0) a0 = __builtin_amdgcn_mfma_f32_16x16x32_f16(w0hh[st], bb, a0, 0, 0, 0);
        a1 = __builtin_amdgcn_mfma_f32_16x16x32_f16(w1ih[st], bb, a1, 0, 0, 0);
      }
      const int Lb = sm->sLens[s & 1][my_b];
      if (doL0) {
        if ((k + 1) <= Lb) {
          float g[4];
#pragma unroll
          for (int gi = 0; gi < 4; ++gi) {
            float xd = 0.f;
#pragma unroll
            for (int j = 0; j < 5; ++j) xd += cwx[gi][j] * sm->X[pp][my_b][j];
            g[gi] = a0[gi] + s0reg[gi] + cb0[gi] + xd;
          }
          float c = sigm(g[1]) * o_c0 + sigm(g[0]) * tanhf(g[2]);
          o_c0 = c; o_h0 = sigm(g[3]) * tanhf(c);
        }
        float hhi0 = __shfl_down(o_h0, 16, 64);
        if (((kq & 1) == 0) && (l15 < 4)) {
          int chunk = my_b * 256 + slot * 8 + wq * 2 + (kq >> 1);
          __hip_atomic_store(&h0T[((k + 1) & 1) * 1024 + chunk],
                             (ull)((unsigned)f16b(o_h0) | ((unsigned)f16b(hhi0) << 16)) |
                             ((ull)sSeq << 32), __ATOMIC_RELAXED, AGT);
        }
      }
      // ---- stage 2: h1 tile, remaining MFMAs, L1 cell, h1 store ----
      if (doPrev) {
        stage4(h1T + ((k - 1) & 1) * 1024, eSeq, B1p);
        __syncthreads();
#pragma unroll
        for (int st = 0; st < 16; ++st)
          a1 = __builtin_amdgcn_mfma_f32_16x16x32_f16(whh[st], ldsB(B1p, st), a1, 0, 0, 0);
      }
      if (k <= Lb) {
        float g[4];
#pragma unroll
        for (int gi = 0; gi < 4; ++gi) g[gi] = a1[gi] + cb1[gi];
        float c = sigm(g[1]) * o_c1 + sigm(g[0]) * tanhf(g[2]);
        o_c1 = c; o_h1 = sigm(g[3]) * tanhf(c);
      }
      float hhi1 = __shfl_down(o_h1, 16, 64);
      if (((kq & 1) == 0) && (l15 < 4)) {
        int chunk = my_b * 256 + slot * 8 + wq * 2 + (kq >> 1);
        __hip_atomic_store(&h1T[(k & 1) * 1024 + chunk],
                           (ull)((unsigned)f16b(o_h1) | ((unsigned)f16b(hhi1) << 16)) |
                           ((ull)sSeq << 32), __ATOMIC_RELAXED, AGT);
      }

      // out(k-1) from staged h1(k-1) (B1p), off the producer critical path
      if (doPrev && oslot && tid < 64) {
        f16x8 hv = *(const f16x8*)((const char*)B1p + b_o * BSTR + lane * 16);
        float sd = 0.f;
#pragma unroll
        for (int j = 0; j < 8; ++j) sd += (float)hv[j] * wo[j];
#pragma unroll
        for (int o2 = 1; o2 < 64; o2 <<= 1) sd += __shfl_xor(sd, o2, 64);
        if (tid == 0) {
          int tt = k - 1;
          float val = 0.f;
          if (tt < sm->sLmax[s & 1])
            val = (tt > sm->sLens[s & 1][b_o]) ? bo_r : (sd + bo_r);
          out[(((4 * team + b_o) * 24 + s) * 48 + tt) * 5 + o_o] = val;
        }
      }
    }
  }
}

extern "C" void kernel_launch(void* const* d_in, const int* in_sizes, int n_in,
                              void* d_out, int out_size, void* d_ws, size_t ws_size,
                              hipStream_t stream) {
  (void)in_sizes; (void)n_in; (void)out_size; (void)ws_size;
  // Pad LDS to 96KB: forces 1 block/CU so the persistent grid maps 1:1 to CUs.
  int lds_bytes = 98304;
  hipFuncSetAttribute((const void*)rnn_decoder_kernel,
                      hipFuncAttributeMaxDynamicSharedMemorySize, lds_bytes);
  // zero all team exchange regions (seq 0 != any expected seq >= 1)
  hipMemsetAsync(d_ws, 0, 8 * 6144 * 8, stream);
  rnn_decoder_kernel<<<dim3(NB), dim3(NT), lds_bytes, stream>>>(
      (const float*)d_in[0],   // enc_features
      (const float*)d_in[1],   // vector_sketch
      (const int*)d_in[3],     // batch_stroke_len
      (const float*)d_in[4],   // W_sc_ih
      (const float*)d_in[5],   // W_sc_hh
      (const float*)d_in[6],   // b_sc
      (const float*)d_in[7],   // W0_ih
      (const float*)d_in[8],   // W0_hh
      (const float*)d_in[9],   // b0
      (const float*)d_in[10],  // W1_ih
      (const float*)d_in[11],  // W1_hh
      (const float*)d_in[12],  // b1
      (const float*)d_in[13],  // W_out
      (const float*)d_in[14],  // b_out
      (float*)d_out, (float*)d_ws);
}